// Round 10
// baseline (268.662 us; speedup 1.0000x reference)
//
#include <hip/hip_runtime.h>
#include <hip/hip_cooperative_groups.h>

namespace cg = cooperative_groups;

// RBCombiner: out[token] = sum of weighted dout_exp rows routed via indices.
// TOP_K = 2 (reference module constant) -> token = idx >> 1.
//
// Ledger (dur_us):
//   R2: split CSR (5 nodes) + simple gather + cached              = 122.9
//   R3: fused setup + 2-unroll + nt ld/st                         = 137.5
//   R4: fused setup + 2-unroll + cached                           = 167.4
//   R6: split CSR + simple gather + nt STORES                     = 111.4
//   R7: bucket-direct (3 nodes: memset+bucket+gather)             =  99.8 <- best
//   R8: R7 + nt row loads                                         =  99.9 (neutral)
// R8 finding: harness reset() writes ~1.3GB between replays -> L3 flushed;
// nt-store win was intra-call RFO elimination, not residency. Traffic is
// minimal; biggest measured lever left = node boundaries (R6->R7: ~11.6us
// for 2 nodes + scan). R9: fuse ALL phases into ONE cooperative kernel
// (zero -> grid.sync -> bucket -> grid.sync -> grid-strided gather).
#define TOPK_SHIFT 1
#define BUCKET_CAP 24
#define GRID_BLKS 1024   // x256 thr = 4096 waves; well under 8192-wave cap

typedef float f32x4 __attribute__((ext_vector_type(4)));

struct Entry { int src; float w; };   // 8 B, read as one dwordx2

// ---------------------------------------------------------------------------
// Fused cooperative kernel.
// Phase 1: zero cursors. Phase 2: bucket entries. Phase 3: gather.
// Entry i in [0, S1+S2) corresponds to dout_exp row i.
//   i <  S1 : token = indices_s1[i] >> 1,                 w = weights[indices_s1[i]]
//   i >= S1 : j=i-S1; token = indices_s1[s1_to_s2[j]]>>1, w = weights[indices_s2[j]]
// ---------------------------------------------------------------------------
__global__ __launch_bounds__(256) void fused_kernel(
    const int* __restrict__ indices_s1,
    const int* __restrict__ indices_s2,
    const int* __restrict__ s1_to_s2,
    const float* __restrict__ weights,
    const f32x4* __restrict__ dout,      // (S1+S2) x D4
    f32x4* __restrict__ out,             // NT x D4
    int* __restrict__ cursors,           // NT
    Entry* __restrict__ buckets,         // NT * BUCKET_CAP
    int S1, int NE, int NT, int D4)
{
    cg::grid_group grid = cg::this_grid();
    const int gtid    = blockIdx.x * blockDim.x + threadIdx.x;
    const int gthreads = gridDim.x * blockDim.x;   // 262144 >= NT, NE

    // ---- Phase 1: zero cursors ----
    for (int i = gtid; i < NT; i += gthreads) cursors[i] = 0;
    grid.sync();

    // ---- Phase 2: bucket entries ----
    for (int i = gtid; i < NE; i += gthreads) {
        int token;
        float w;
        if (i < S1) {
            int idx = indices_s1[i];
            token = idx >> TOPK_SHIFT;
            w = weights[idx];
        } else {
            int j = i - S1;
            token = indices_s1[s1_to_s2[j]] >> TOPK_SHIFT;
            w = weights[indices_s2[j]];
        }
        int pos = atomicAdd(&cursors[token], 1);
        if (pos < BUCKET_CAP) {
            Entry e; e.src = i; e.w = w;
            buckets[token * BUCKET_CAP + pos] = e;
        }
    }
    grid.sync();

    // ---- Phase 3: gather (grid-strided over tokens) ----
    const int tid = threadIdx.x;
    if ((D4 & 1023) == 0) {
        for (int t = blockIdx.x; t < NT; t += gridDim.x) {
            int n = cursors[t];
            n = (n < BUCKET_CAP) ? n : BUCKET_CAP;
            const Entry* b = buckets + t * BUCKET_CAP;
            for (int base = 0; base < D4; base += 1024) {
                f32x4 a0 = 0, a1 = 0, a2 = 0, a3 = 0;
                for (int e = 0; e < n; ++e) {
                    const Entry en = b[e];                 // 8B broadcast load
                    const float w = en.w;
                    const f32x4* row = dout + (size_t)en.src * (size_t)D4 + base;
                    f32x4 v0 = __builtin_nontemporal_load(row + tid);
                    f32x4 v1 = __builtin_nontemporal_load(row + tid + 256);
                    f32x4 v2 = __builtin_nontemporal_load(row + tid + 512);
                    f32x4 v3 = __builtin_nontemporal_load(row + tid + 768);
                    a0 += w * v0;
                    a1 += w * v1;
                    a2 += w * v2;
                    a3 += w * v3;
                }
                f32x4* orow = out + (size_t)t * (size_t)D4 + base;
                __builtin_nontemporal_store(a0, orow + tid);
                __builtin_nontemporal_store(a1, orow + tid + 256);
                __builtin_nontemporal_store(a2, orow + tid + 512);
                __builtin_nontemporal_store(a3, orow + tid + 768);
            }
        }
    } else {
        // generic fallback (not hit for D=4096)
        for (int t = blockIdx.x; t < NT; t += gridDim.x) {
            int n = cursors[t];
            n = (n < BUCKET_CAP) ? n : BUCKET_CAP;
            const Entry* b = buckets + t * BUCKET_CAP;
            for (int c = tid; c < D4; c += 256) {
                f32x4 acc = 0;
                for (int e = 0; e < n; ++e)
                    acc += b[e].w * __builtin_nontemporal_load(
                               dout + (size_t)b[e].src * (size_t)D4 + c);
                __builtin_nontemporal_store(acc, out + (size_t)t * (size_t)D4 + c);
            }
        }
    }
}

// ---------------------------------------------------------------------------
// Launch. Inputs (setup_inputs order):
//   0: dout_exp (S1+S2, D) f32 | 1: weights (S1,) f32 | 2: indices_s1 (S1,)
//   3: indices_s2 (S2,) | 4: s1exp_to_s2_indices (S2,) | 5: n_tokens scalar
// ---------------------------------------------------------------------------
extern "C" void kernel_launch(void* const* d_in, const int* in_sizes, int n_in,
                              void* d_out, int out_size, void* d_ws, size_t ws_size,
                              hipStream_t stream) {
    const float* dout_exp   = (const float*)d_in[0];
    const float* weights    = (const float*)d_in[1];
    const int*   indices_s1 = (const int*)d_in[2];
    const int*   indices_s2 = (const int*)d_in[3];
    const int*   s1_to_s2   = (const int*)d_in[4];

    const int S1    = in_sizes[1];          // 16384
    const int S2    = in_sizes[3];          // 4096
    const int NROWS = S1 + S2;
    const int D     = in_sizes[0] / NROWS;  // 4096
    const int NT    = out_size / D;         // 8192
    const int D4    = D / 4;
    const int NE    = NROWS;                // 20480 entries

    // Workspace: cursors (NT ints, 32 KB) | buckets (NT*24*8 B = 1.5 MB)
    int*   cursors = (int*)d_ws;
    Entry* buckets = (Entry*)(cursors + NT);

    const f32x4* dout4 = (const f32x4*)dout_exp;
    f32x4*       out4  = (f32x4*)d_out;

    void* args[] = {
        (void*)&indices_s1, (void*)&indices_s2, (void*)&s1_to_s2,
        (void*)&weights, (void*)&dout4, (void*)&out4,
        (void*)&cursors, (void*)&buckets,
        (void*)&S1, (void*)&NE, (void*)&NT, (void*)&D4
    };
    (void)hipLaunchCooperativeKernel((void*)fused_kernel,
                                     dim3(GRID_BLKS), dim3(256),
                                     args, 0, stream);
}

// Round 11
// 97.538 us; speedup vs baseline: 2.7544x; 2.7544x over previous
//
#include <hip/hip_runtime.h>

// RBCombiner: out[token] = sum of weighted dout_exp rows routed via indices.
// TOP_K = 2 (reference module constant) -> token = idx >> 1.
//
// Ledger (dur_us):
//   R2: split CSR (5 nodes) + simple gather + cached              = 122.9
//   R3: fused setup + 2-unroll + nt ld/st                         = 137.5
//   R4: fused setup + 2-unroll + cached                           = 167.4
//   R6: split CSR + simple gather + nt STORES                     = 111.4
//   R7: bucket-direct (3 nodes: memset+bucket+gather)             =  99.8 <- best
//   R8: R7 + nt row loads                                         =  99.9 (neutral)
//   R9: cooperative 1-kernel fusion (1024 blk, grid.sync)         = 268.7 (2.7x REGRESSION
//       — co-op machinery / grid-stride serialization; BW model failed; abandoned)
// R10: revert to R8 structure; single change: HALF-ROW gather decomposition
// (16384 blocks, token=bid>>1, 2 f32x4/thread). Probes the latency/issue
// component hinted by R9's anomaly while halving tail stragglers.
#define TOPK_SHIFT 1
#define BUCKET_CAP 24

typedef float f32x4 __attribute__((ext_vector_type(4)));

struct Entry { int src; float w; };   // 8 B, read as one dwordx2

// ---------------------------------------------------------------------------
// K1: route every entry directly into its token's bucket.
// Entry i in [0, S1+S2) corresponds to dout_exp row i.
//   i <  S1 : token = indices_s1[i] >> 1,                 w = weights[indices_s1[i]]
//   i >= S1 : j=i-S1; token = indices_s1[s1_to_s2[j]]>>1, w = weights[indices_s2[j]]
// ---------------------------------------------------------------------------
__global__ void bucket_kernel(
    const int* __restrict__ indices_s1,
    const int* __restrict__ indices_s2,
    const int* __restrict__ s1_to_s2,
    const float* __restrict__ weights,
    int S1, int NE,
    int* __restrict__ cursors,          // NT, pre-zeroed
    Entry* __restrict__ buckets)        // NT * BUCKET_CAP
{
    int i = blockIdx.x * blockDim.x + threadIdx.x;
    if (i >= NE) return;
    int token;
    float w;
    if (i < S1) {
        int idx = indices_s1[i];
        token = idx >> TOPK_SHIFT;
        w = weights[idx];
    } else {
        int j = i - S1;
        token = indices_s1[s1_to_s2[j]] >> TOPK_SHIFT;
        w = weights[indices_s2[j]];
    }
    int pos = atomicAdd(&cursors[token], 1);
    if (pos < BUCKET_CAP) {
        Entry e; e.src = i; e.w = w;
        buckets[token * BUCKET_CAP + pos] = e;
    }
}

// ---------------------------------------------------------------------------
// K2: half-row gather. TWO blocks per token (bid>>1 = token, bid&1 = half);
// each block's thread owns 2 f32x4 lanes (stride-256 interleave, 16 B/lane
// coalesced). 2x independent block pipelines vs R7 (cold-start chains
// overlap more, tail stragglers halve). NT row loads (R8: neutral) and NT
// stores (R6: -11.5us, intra-call RFO elimination). Entry/cursor loads
// cached (tiny, L2-resident; read twice now — negligible).
// ---------------------------------------------------------------------------
__global__ __launch_bounds__(256) void gather_kernel(
    const f32x4* __restrict__ dout,      // (S1+S2) x D4
    const int*   __restrict__ cursors,   // NT (counts)
    const Entry* __restrict__ buckets,   // NT * BUCKET_CAP
    f32x4*       __restrict__ out,       // NT x D4
    int D4)
{
    const int bid = blockIdx.x;
    const int t   = bid >> 1;            // token
    const int h   = bid & 1;             // which half of the row
    const int tid = threadIdx.x;
    int n = cursors[t];
    n = (n < BUCKET_CAP) ? n : BUCKET_CAP;
    const Entry* b = buckets + t * BUCKET_CAP;

    if ((D4 & 1023) == 0) {
        // fast path: D4 multiple of 1024 (D=4096 -> one chunk). Block h
        // covers [chunk + h*512, +512) of each 1024-wide chunk.
        for (int chunk = 0; chunk < D4; chunk += 1024) {
            const int base = chunk + h * 512;
            f32x4 a0 = 0, a1 = 0;
            for (int e = 0; e < n; ++e) {
                const Entry en = b[e];                 // 8B broadcast load
                const float w = en.w;
                const f32x4* row = dout + (size_t)en.src * (size_t)D4 + base;
                f32x4 v0 = __builtin_nontemporal_load(row + tid);
                f32x4 v1 = __builtin_nontemporal_load(row + tid + 256);
                a0 += w * v0;
                a1 += w * v1;
            }
            f32x4* orow = out + (size_t)t * (size_t)D4 + base;
            __builtin_nontemporal_store(a0, orow + tid);
            __builtin_nontemporal_store(a1, orow + tid + 256);
        }
    } else {
        // generic fallback (not hit for D=4096): half h covers its column range
        const int lo = (D4 * h) / 2;
        const int hi = (D4 * (h + 1)) / 2;
        for (int c = lo + tid; c < hi; c += 256) {
            f32x4 acc = 0;
            for (int e = 0; e < n; ++e)
                acc += b[e].w * __builtin_nontemporal_load(
                           dout + (size_t)b[e].src * (size_t)D4 + c);
            __builtin_nontemporal_store(acc, out + (size_t)t * (size_t)D4 + c);
        }
    }
}

// ---------------------------------------------------------------------------
// Launch. Inputs (setup_inputs order):
//   0: dout_exp (S1+S2, D) f32 | 1: weights (S1,) f32 | 2: indices_s1 (S1,)
//   3: indices_s2 (S2,) | 4: s1exp_to_s2_indices (S2,) | 5: n_tokens scalar
// ---------------------------------------------------------------------------
extern "C" void kernel_launch(void* const* d_in, const int* in_sizes, int n_in,
                              void* d_out, int out_size, void* d_ws, size_t ws_size,
                              hipStream_t stream) {
    const float* dout_exp   = (const float*)d_in[0];
    const float* weights    = (const float*)d_in[1];
    const int*   indices_s1 = (const int*)d_in[2];
    const int*   indices_s2 = (const int*)d_in[3];
    const int*   s1_to_s2   = (const int*)d_in[4];

    const int S1    = in_sizes[1];          // 16384
    const int S2    = in_sizes[3];          // 4096
    const int NROWS = S1 + S2;
    const int D     = in_sizes[0] / NROWS;  // 4096
    const int NT    = out_size / D;         // 8192
    const int D4    = D / 4;
    const int NE    = NROWS;                // 20480 entries

    // Workspace: cursors (NT ints, 32 KB) | buckets (NT*24*8 B = 1.5 MB)
    int*   cursors = (int*)d_ws;
    Entry* buckets = (Entry*)(cursors + NT);

    // Re-zero cursors every call (graph-replay safe).
    (void)hipMemsetAsync(cursors, 0, (size_t)NT * sizeof(int), stream);

    const int threads = 256;
    const int eblocks = (NE + threads - 1) / threads;

    bucket_kernel<<<eblocks, threads, 0, stream>>>(
        indices_s1, indices_s2, s1_to_s2, weights, S1, NE,
        cursors, buckets);

    gather_kernel<<<NT * 2, 256, 0, stream>>>(
        (const f32x4*)dout_exp, cursors, buckets,
        (f32x4*)d_out, D4);
}